// Round 9
// baseline (31.529 us; speedup 1.0000x reference)
//
#include <hip/hip_runtime.h>
#include <math.h>

// Morph2d: weighted 3x3 window min/max lerp.
// s = x_pad + 10*bias[c] (pad cell -> biasv, raw pad = 0); tap = s * k[c,i,j]
// out = vmin + (vmax - vmin) * sigmoid(10*percentile[c]) - 10*bias[c]
//
// R9 = R4 structure (8x4 tile/thread, all 6 input rows preloaded -> 24
// independent loads in flight, no launch_bounds VGPR cap) with:
//  (1) PLAIN stores (not nontemporal): in the warm replay loop input+output
//      (103 MB) fit the 256 MB L3; allocating stores let output lines stay
//      dirty-resident instead of forcing ~51 MB HBM write per replay.
//  (2) __expf fast sigmoid (cuts ~30-instr serial setup chain per thread).

#define B_ 16
#define C_ 64
#define H_ 112
#define W_ 112
#define TW 8
#define TH 4
#define GX (W_ / TW)   // 14
#define GY (H_ / TH)   // 28

typedef float f32x4 __attribute__((ext_vector_type(4)));

__global__ __launch_bounds__(256) void morph2d_kernel(
    const float* __restrict__ x,
    const float* __restrict__ kern,   // (1,C,3,3)
    const float* __restrict__ bias,   // (C,)
    const float* __restrict__ perc,   // (C,)
    float* __restrict__ out)
{
    const int total = B_ * C_ * GY * GX;  // 401,408
    int t = blockIdx.x * blockDim.x + threadIdx.x;
    if (t >= total) return;

    int gx = t % GX;
    int r1 = t / GX;
    int ys = r1 % GY;
    int bc = r1 / GY;       // b*C + c
    int c  = bc % C_;

    float biasv = bias[c] * 10.0f;
    float p = 1.0f / (1.0f + __expf(-perc[c] * 10.0f));

    const float* plane  = x   + (size_t)bc * (H_ * W_);
    float*       oplane = out + (size_t)bc * (H_ * W_);
    const int x0 = gx * TW;
    const int y0 = ys * TH;

    // Preload all TH+2 = 6 rows, cols x0-1 .. x0+8, biasv pre-added
    // (pad cell == biasv). All loads independent -> max MLP, one vmcnt wait.
    float s[TH + 2][TW + 2];
    #pragma unroll
    for (int i = 0; i < TH + 2; ++i) {
        int yy = y0 + i - 1;
        if ((unsigned)yy < (unsigned)H_) {
            const float* rp = plane + yy * W_ + x0;
            f32x4 a  = *reinterpret_cast<const f32x4*>(rp);
            f32x4 b4 = *reinterpret_cast<const f32x4*>(rp + 4);
            s[i][1] = a.x  + biasv;  s[i][2] = a.y  + biasv;
            s[i][3] = a.z  + biasv;  s[i][4] = a.w  + biasv;
            s[i][5] = b4.x + biasv;  s[i][6] = b4.y + biasv;
            s[i][7] = b4.z + biasv;  s[i][8] = b4.w + biasv;
            s[i][0] = (x0 > 0)       ? rp[-1] + biasv : biasv;
            s[i][9] = (x0 + TW < W_) ? rp[TW] + biasv : biasv;
        } else {
            #pragma unroll
            for (int j = 0; j < TW + 2; ++j) s[i][j] = biasv;
        }
    }

    float k[9];
    #pragma unroll
    for (int i = 0; i < 9; ++i) k[i] = kern[c * 9 + i];

    #pragma unroll
    for (int r = 0; r < TH; ++r) {
        float o[TW];
        #pragma unroll
        for (int q = 0; q < TW; ++q) {
            float t0 = s[r][q]     * k[0];
            float t1 = s[r][q + 1] * k[1];
            float t2 = s[r][q + 2] * k[2];
            float vmax = fmaxf(fmaxf(t0, t1), t2);
            float vmin = fminf(fminf(t0, t1), t2);
            t0 = s[r + 1][q]     * k[3];
            t1 = s[r + 1][q + 1] * k[4];
            t2 = s[r + 1][q + 2] * k[5];
            vmax = fmaxf(vmax, fmaxf(fmaxf(t0, t1), t2));
            vmin = fminf(vmin, fminf(fminf(t0, t1), t2));
            t0 = s[r + 2][q]     * k[6];
            t1 = s[r + 2][q + 1] * k[7];
            t2 = s[r + 2][q + 2] * k[8];
            vmax = fmaxf(vmax, fmaxf(fmaxf(t0, t1), t2));
            vmin = fminf(vmin, fminf(fminf(t0, t1), t2));
            o[q] = fmaf(vmax - vmin, p, vmin) - biasv;
        }

        float* orow = oplane + (y0 + r) * W_ + x0;
        *reinterpret_cast<f32x4*>(orow)     = f32x4{ o[0], o[1], o[2], o[3] };
        *reinterpret_cast<f32x4*>(orow + 4) = f32x4{ o[4], o[5], o[6], o[7] };
    }
}

extern "C" void kernel_launch(void* const* d_in, const int* in_sizes, int n_in,
                              void* d_out, int out_size, void* d_ws, size_t ws_size,
                              hipStream_t stream) {
    const float* x    = (const float*)d_in[0];
    const float* kern = (const float*)d_in[1];
    const float* bias = (const float*)d_in[2];
    const float* perc = (const float*)d_in[3];
    float* out = (float*)d_out;

    const int total = B_ * C_ * GY * GX;              // 401,408
    const int block = 256;
    const int grid  = (total + block - 1) / block;    // 1568
    morph2d_kernel<<<grid, block, 0, stream>>>(x, kern, bias, perc, out);
}

// Round 10
// 22.847 us; speedup vs baseline: 1.3800x; 1.3800x over previous
//
#include <hip/hip_runtime.h>
#include <math.h>

// Morph2d: weighted 3x3 window min/max lerp.
// tap(i,j) = raw*k + bk  (bk = 10*bias*k; raw pad = 0)
// out = vmin + (vmax - vmin) * sigmoid(10*percentile[c]) - 10*bias[c]
//
// R10: dense lane mapping + phase-separated shuffle halos.
//  - thread = 4-wide (one f32x4) x 4-tall tile; 32-lane row-groups cover a
//    full 112-px row strip (28 active lanes + 4 clamped duplicates).
//  - Phase 1: issue ALL 6 clamped-row f32x4 loads (independent -> full MLP,
//    the property that made R4 win). Phase 2: mask + 2 shuffles per row for
//    the x-halos (group-crossing shuffle values are only ever consumed at
//    x=-1/x=112, which are pads -> masked to 0).
//  - 10 VMEM instrs per wave (vs R4's 32), all lane-dense; NT stores (proven
//    faster than plain in R4 vs R9).

#define B_ 16
#define C_ 64
#define H_ 112
#define W_ 112

typedef float f32x4 __attribute__((ext_vector_type(4)));

__global__ __launch_bounds__(256) void morph2d_kernel(
    const float* __restrict__ x,
    const float* __restrict__ kern,   // (1,C,3,3)
    const float* __restrict__ bias,   // (C,)
    const float* __restrict__ perc,   // (C,)
    float* __restrict__ out)
{
    const int t      = blockIdx.x * blockDim.x + threadIdx.x;
    const int lane32 = t & 31;
    const int group  = t >> 5;             // 0..28671  (bc, ytile)
    const bool active = (lane32 < 28);
    const int gx = active ? lane32 : 27;   // duplicates clamp to gx=27
    const int ytile = group % 28;
    const int bc    = group / 28;          // b*C + c
    const int c     = bc & (C_ - 1);
    const int x0 = gx * 4;
    const int y0 = ytile * 4;

    const float biasv = bias[c] * 10.0f;
    const float p = 1.0f / (1.0f + __expf(-perc[c] * 10.0f));

    float k[9], bk[9];
    #pragma unroll
    for (int i = 0; i < 9; ++i) {
        k[i]  = kern[c * 9 + i];
        bk[i] = k[i] * biasv;
    }

    const float* plane = x + (size_t)bc * (H_ * W_);

    // ---- phase 1: 6 independent clamped-row loads (no consumers yet) ----
    f32x4 v[6];
    #pragma unroll
    for (int i = 0; i < 6; ++i) {
        int yy  = y0 + i - 1;
        int yyc = yy < 0 ? 0 : (yy > H_ - 1 ? H_ - 1 : yy);
        v[i] = *reinterpret_cast<const f32x4*>(plane + yyc * W_ + x0);
    }

    // ---- phase 2: mask pads, shuffle halos -> 6x6 raw window ----
    float s[6][6];
    #pragma unroll
    for (int i = 0; i < 6; ++i) {
        int yy = y0 + i - 1;
        const bool inY = ((unsigned)yy < (unsigned)H_);   // uniform per group
        float rx = inY ? v[i].x : 0.0f;
        float ry = inY ? v[i].y : 0.0f;
        float rz = inY ? v[i].z : 0.0f;
        float rw = inY ? v[i].w : 0.0f;
        float left  = __shfl_up(rw, 1);    // prev lane's x0+3 == our x0-1
        float right = __shfl_down(rx, 1);  // next lane's x0   == our x0+4
        s[i][0] = (gx > 0)  ? left  : 0.0f;
        s[i][1] = rx; s[i][2] = ry; s[i][3] = rz; s[i][4] = rw;
        s[i][5] = (gx < 27) ? right : 0.0f;
    }

    // ---- compute 4 rows x 4 outputs, NT store one f32x4 per row ----
    float* oplane = out + (size_t)bc * (H_ * W_);
    #pragma unroll
    for (int r = 0; r < 4; ++r) {
        float o[4];
        #pragma unroll
        for (int q = 0; q < 4; ++q) {
            float t0 = fmaf(s[r][q],     k[0], bk[0]);
            float t1 = fmaf(s[r][q + 1], k[1], bk[1]);
            float t2 = fmaf(s[r][q + 2], k[2], bk[2]);
            float vmax = fmaxf(fmaxf(t0, t1), t2);
            float vmin = fminf(fminf(t0, t1), t2);
            t0 = fmaf(s[r + 1][q],     k[3], bk[3]);
            t1 = fmaf(s[r + 1][q + 1], k[4], bk[4]);
            t2 = fmaf(s[r + 1][q + 2], k[5], bk[5]);
            vmax = fmaxf(vmax, fmaxf(fmaxf(t0, t1), t2));
            vmin = fminf(vmin, fminf(fminf(t0, t1), t2));
            t0 = fmaf(s[r + 2][q],     k[6], bk[6]);
            t1 = fmaf(s[r + 2][q + 1], k[7], bk[7]);
            t2 = fmaf(s[r + 2][q + 2], k[8], bk[8]);
            vmax = fmaxf(vmax, fmaxf(fmaxf(t0, t1), t2));
            vmin = fminf(vmin, fminf(fminf(t0, t1), t2));
            o[q] = fmaf(vmax - vmin, p, vmin) - biasv;
        }
        if (active) {
            f32x4 ov = { o[0], o[1], o[2], o[3] };
            __builtin_nontemporal_store(
                ov, reinterpret_cast<f32x4*>(oplane + (y0 + r) * W_ + x0));
        }
    }
}

extern "C" void kernel_launch(void* const* d_in, const int* in_sizes, int n_in,
                              void* d_out, int out_size, void* d_ws, size_t ws_size,
                              hipStream_t stream) {
    const float* x    = (const float*)d_in[0];
    const float* kern = (const float*)d_in[1];
    const float* bias = (const float*)d_in[2];
    const float* perc = (const float*)d_in[3];
    float* out = (float*)d_out;

    // 28672 groups of 32 lanes = 917,504 threads
    const int threads = (B_ * C_ * 28) * 32;
    const int block = 256;
    const int grid  = threads / block;     // 3584
    morph2d_kernel<<<grid, block, 0, stream>>>(x, kern, bias, perc, out);
}

// Round 11
// 22.448 us; speedup vs baseline: 1.4045x; 1.0178x over previous
//
#include <hip/hip_runtime.h>
#include <math.h>

// Morph2d: weighted 3x3 window min/max lerp.
// tap(i,j) = raw*k + bk  (bk = 10*bias*k; raw pad = 0)
// out = vmin + (vmax - vmin) * sigmoid(10*percentile[c]) - 10*bias[c]
//
// R11 = R10 structure with TH=8 (was 4):
//  - thread = 4-wide (one f32x4) x 8-tall tile; 32-lane row-groups cover a
//    full 112-px row strip (28 active lanes + 4 clamped duplicates).
//  - Phase 1: ALL 10 clamped-row f32x4 loads issued independently (full MLP).
//  - Phase 2: two 4-row compute chunks (static v[] indexing after unroll);
//    mask + 2 shuffles per window row; NT stores (proven R4 vs R9).
//  - read amplification 10/8 = 1.25x (was 6/4 = 1.5x); setup amortized
//    over 32 outputs (was 16).

#define B_ 16
#define C_ 64
#define H_ 112
#define W_ 112
#define TH 8
#define GYT (H_ / TH)   // 14 y-tiles

typedef float f32x4 __attribute__((ext_vector_type(4)));

__global__ __launch_bounds__(256) void morph2d_kernel(
    const float* __restrict__ x,
    const float* __restrict__ kern,   // (1,C,3,3)
    const float* __restrict__ bias,   // (C,)
    const float* __restrict__ perc,   // (C,)
    float* __restrict__ out)
{
    const int t      = blockIdx.x * blockDim.x + threadIdx.x;
    const int lane32 = t & 31;
    const int group  = t >> 5;             // 0..14335  (bc, ytile)
    const bool active = (lane32 < 28);
    const int gx = active ? lane32 : 27;   // duplicates clamp to gx=27
    const int ytile = group % GYT;
    const int bc    = group / GYT;         // b*C + c
    const int c     = bc & (C_ - 1);
    const int x0 = gx * 4;
    const int y0 = ytile * TH;

    const float biasv = bias[c] * 10.0f;
    const float p = 1.0f / (1.0f + __expf(-perc[c] * 10.0f));

    float k[9], bk[9];
    #pragma unroll
    for (int i = 0; i < 9; ++i) {
        k[i]  = kern[c * 9 + i];
        bk[i] = k[i] * biasv;
    }

    const float* plane = x + (size_t)bc * (H_ * W_);

    // ---- phase 1: 10 independent clamped-row loads (no consumers yet) ----
    f32x4 v[TH + 2];
    #pragma unroll
    for (int i = 0; i < TH + 2; ++i) {
        int yy  = y0 + i - 1;
        int yyc = yy < 0 ? 0 : (yy > H_ - 1 ? H_ - 1 : yy);
        v[i] = *reinterpret_cast<const f32x4*>(plane + yyc * W_ + x0);
    }

    float* oplane = out + (size_t)bc * (H_ * W_);

    // ---- phase 2: two 4-row chunks; mask + shuffle halos, compute, store ----
    #pragma unroll
    for (int ch = 0; ch < 2; ++ch) {
        float s[6][6];
        #pragma unroll
        for (int i = 0; i < 6; ++i) {
            int yy = y0 + 4 * ch + i - 1;
            const bool inY = ((unsigned)yy < (unsigned)H_);  // uniform per group
            f32x4 vv = v[4 * ch + i];
            float rx = inY ? vv.x : 0.0f;
            float ry = inY ? vv.y : 0.0f;
            float rz = inY ? vv.z : 0.0f;
            float rw = inY ? vv.w : 0.0f;
            float left  = __shfl_up(rw, 1);    // prev lane's x0+3 == our x0-1
            float right = __shfl_down(rx, 1);  // next lane's x0   == our x0+4
            s[i][0] = (gx > 0)  ? left  : 0.0f;
            s[i][1] = rx; s[i][2] = ry; s[i][3] = rz; s[i][4] = rw;
            s[i][5] = (gx < 27) ? right : 0.0f;
        }

        #pragma unroll
        for (int r = 0; r < 4; ++r) {
            float o[4];
            #pragma unroll
            for (int q = 0; q < 4; ++q) {
                float t0 = fmaf(s[r][q],     k[0], bk[0]);
                float t1 = fmaf(s[r][q + 1], k[1], bk[1]);
                float t2 = fmaf(s[r][q + 2], k[2], bk[2]);
                float vmax = fmaxf(fmaxf(t0, t1), t2);
                float vmin = fminf(fminf(t0, t1), t2);
                t0 = fmaf(s[r + 1][q],     k[3], bk[3]);
                t1 = fmaf(s[r + 1][q + 1], k[4], bk[4]);
                t2 = fmaf(s[r + 1][q + 2], k[5], bk[5]);
                vmax = fmaxf(vmax, fmaxf(fmaxf(t0, t1), t2));
                vmin = fminf(vmin, fminf(fminf(t0, t1), t2));
                t0 = fmaf(s[r + 2][q],     k[6], bk[6]);
                t1 = fmaf(s[r + 2][q + 1], k[7], bk[7]);
                t2 = fmaf(s[r + 2][q + 2], k[8], bk[8]);
                vmax = fmaxf(vmax, fmaxf(fmaxf(t0, t1), t2));
                vmin = fminf(vmin, fminf(fminf(t0, t1), t2));
                o[q] = fmaf(vmax - vmin, p, vmin) - biasv;
            }
            if (active) {
                f32x4 ov = { o[0], o[1], o[2], o[3] };
                __builtin_nontemporal_store(
                    ov, reinterpret_cast<f32x4*>(
                            oplane + (y0 + 4 * ch + r) * W_ + x0));
            }
        }
    }
}

extern "C" void kernel_launch(void* const* d_in, const int* in_sizes, int n_in,
                              void* d_out, int out_size, void* d_ws, size_t ws_size,
                              hipStream_t stream) {
    const float* x    = (const float*)d_in[0];
    const float* kern = (const float*)d_in[1];
    const float* bias = (const float*)d_in[2];
    const float* perc = (const float*)d_in[3];
    float* out = (float*)d_out;

    // 14336 groups of 32 lanes = 458,752 threads
    const int threads = (B_ * C_ * GYT) * 32;
    const int block = 256;
    const int grid  = threads / block;     // 1792
    morph2d_kernel<<<grid, block, 0, stream>>>(x, kern, bias, perc, out);
}

// Round 12
// 22.063 us; speedup vs baseline: 1.4291x; 1.0175x over previous
//
#include <hip/hip_runtime.h>
#include <math.h>

// Morph2d: weighted 3x3 window min/max lerp.
// tap(i,j) = raw*k + bk  (bk = 10*bias*k; raw pad = 0)
// out = vmin + (vmax - vmin) * sigmoid(10*percentile[c]) - 10*bias[c]
//
// R12 = R11 with PLAIN stores (single-variable A/B vs NT).
// Rationale: R10/R11 are the first fully DENSE store layouts (consecutive
// lanes -> consecutive 16B, full 64B lines), so allocating stores pay no
// partial-line penalty — and out+in (103 MB) fit the 256 MB L3, so dirty
// output lines may stay cache-resident across graph replays, eliminating
// ~51 MB of HBM write per replay. All prior plain-store tests (R6/R8/R9)
// were on strided layouts and don't answer this.

#define B_ 16
#define C_ 64
#define H_ 112
#define W_ 112
#define TH 8
#define GYT (H_ / TH)   // 14 y-tiles

typedef float f32x4 __attribute__((ext_vector_type(4)));

__global__ __launch_bounds__(256) void morph2d_kernel(
    const float* __restrict__ x,
    const float* __restrict__ kern,   // (1,C,3,3)
    const float* __restrict__ bias,   // (C,)
    const float* __restrict__ perc,   // (C,)
    float* __restrict__ out)
{
    const int t      = blockIdx.x * blockDim.x + threadIdx.x;
    const int lane32 = t & 31;
    const int group  = t >> 5;             // 0..14335  (bc, ytile)
    const bool active = (lane32 < 28);
    const int gx = active ? lane32 : 27;   // duplicates clamp to gx=27
    const int ytile = group % GYT;
    const int bc    = group / GYT;         // b*C + c
    const int c     = bc & (C_ - 1);
    const int x0 = gx * 4;
    const int y0 = ytile * TH;

    const float biasv = bias[c] * 10.0f;
    const float p = 1.0f / (1.0f + __expf(-perc[c] * 10.0f));

    float k[9], bk[9];
    #pragma unroll
    for (int i = 0; i < 9; ++i) {
        k[i]  = kern[c * 9 + i];
        bk[i] = k[i] * biasv;
    }

    const float* plane = x + (size_t)bc * (H_ * W_);

    // ---- phase 1: 10 independent clamped-row loads (no consumers yet) ----
    f32x4 v[TH + 2];
    #pragma unroll
    for (int i = 0; i < TH + 2; ++i) {
        int yy  = y0 + i - 1;
        int yyc = yy < 0 ? 0 : (yy > H_ - 1 ? H_ - 1 : yy);
        v[i] = *reinterpret_cast<const f32x4*>(plane + yyc * W_ + x0);
    }

    float* oplane = out + (size_t)bc * (H_ * W_);

    // ---- phase 2: two 4-row chunks; mask + shuffle halos, compute, store ----
    #pragma unroll
    for (int ch = 0; ch < 2; ++ch) {
        float s[6][6];
        #pragma unroll
        for (int i = 0; i < 6; ++i) {
            int yy = y0 + 4 * ch + i - 1;
            const bool inY = ((unsigned)yy < (unsigned)H_);  // uniform per group
            f32x4 vv = v[4 * ch + i];
            float rx = inY ? vv.x : 0.0f;
            float ry = inY ? vv.y : 0.0f;
            float rz = inY ? vv.z : 0.0f;
            float rw = inY ? vv.w : 0.0f;
            float left  = __shfl_up(rw, 1);    // prev lane's x0+3 == our x0-1
            float right = __shfl_down(rx, 1);  // next lane's x0   == our x0+4
            s[i][0] = (gx > 0)  ? left  : 0.0f;
            s[i][1] = rx; s[i][2] = ry; s[i][3] = rz; s[i][4] = rw;
            s[i][5] = (gx < 27) ? right : 0.0f;
        }

        #pragma unroll
        for (int r = 0; r < 4; ++r) {
            float o[4];
            #pragma unroll
            for (int q = 0; q < 4; ++q) {
                float t0 = fmaf(s[r][q],     k[0], bk[0]);
                float t1 = fmaf(s[r][q + 1], k[1], bk[1]);
                float t2 = fmaf(s[r][q + 2], k[2], bk[2]);
                float vmax = fmaxf(fmaxf(t0, t1), t2);
                float vmin = fminf(fminf(t0, t1), t2);
                t0 = fmaf(s[r + 1][q],     k[3], bk[3]);
                t1 = fmaf(s[r + 1][q + 1], k[4], bk[4]);
                t2 = fmaf(s[r + 1][q + 2], k[5], bk[5]);
                vmax = fmaxf(vmax, fmaxf(fmaxf(t0, t1), t2));
                vmin = fminf(vmin, fminf(fminf(t0, t1), t2));
                t0 = fmaf(s[r + 2][q],     k[6], bk[6]);
                t1 = fmaf(s[r + 2][q + 1], k[7], bk[7]);
                t2 = fmaf(s[r + 2][q + 2], k[8], bk[8]);
                vmax = fmaxf(vmax, fmaxf(fmaxf(t0, t1), t2));
                vmin = fminf(vmin, fminf(fminf(t0, t1), t2));
                o[q] = fmaf(vmax - vmin, p, vmin) - biasv;
            }
            if (active) {
                f32x4 ov = { o[0], o[1], o[2], o[3] };
                *reinterpret_cast<f32x4*>(
                    oplane + (y0 + 4 * ch + r) * W_ + x0) = ov;
            }
        }
    }
}

extern "C" void kernel_launch(void* const* d_in, const int* in_sizes, int n_in,
                              void* d_out, int out_size, void* d_ws, size_t ws_size,
                              hipStream_t stream) {
    const float* x    = (const float*)d_in[0];
    const float* kern = (const float*)d_in[1];
    const float* bias = (const float*)d_in[2];
    const float* perc = (const float*)d_in[3];
    float* out = (float*)d_out;

    // 14336 groups of 32 lanes = 458,752 threads
    const int threads = (B_ * C_ * GYT) * 32;
    const int block = 256;
    const int grid  = threads / block;     // 1792
    morph2d_kernel<<<grid, block, 0, stream>>>(x, kern, bias, perc, out);
}

// Round 13
// 21.739 us; speedup vs baseline: 1.4503x; 1.0149x over previous
//
#include <hip/hip_runtime.h>
#include <math.h>

// Morph2d: weighted 3x3 window min/max lerp.
// tap(i,j) = raw*k + bk  (bk = 10*bias*k; raw pad = 0)
// out = vmin + (vmax - vmin) * sigmoid(10*percentile[c]) - 10*bias[c]
//
// R13 = R12 mapping (32-lane row-groups, 28 active, 4-wide x 8-tall tile,
// phase-separated loads, plain dense stores) with leaner dataflow:
//  - y-pad via wholesale zeroing of v[0]/v[9] under UNIFORM ytile branch
//    (replaces 48 per-element selects)
//  - halo arrays L[10]/R[10] built once with 20 shuffles (was 24), no
//    s[6][6] materialization: taps read L/v/R directly in one 8-row pass

#define B_ 16
#define C_ 64
#define H_ 112
#define W_ 112
#define TH 8
#define GYT (H_ / TH)   // 14 y-tiles

typedef float f32x4 __attribute__((ext_vector_type(4)));

__global__ __launch_bounds__(256) void morph2d_kernel(
    const float* __restrict__ x,
    const float* __restrict__ kern,   // (1,C,3,3)
    const float* __restrict__ bias,   // (C,)
    const float* __restrict__ perc,   // (C,)
    float* __restrict__ out)
{
    const int t      = blockIdx.x * blockDim.x + threadIdx.x;
    const int lane32 = t & 31;
    const int group  = t >> 5;             // 0..14335  (bc, ytile)
    const bool active = (lane32 < 28);
    const int gx = active ? lane32 : 27;   // duplicates clamp to gx=27
    const int ytile = group % GYT;
    const int bc    = group / GYT;         // b*C + c
    const int c     = bc & (C_ - 1);
    const int x0 = gx * 4;
    const int y0 = ytile * TH;

    const float biasv = bias[c] * 10.0f;
    const float p = 1.0f / (1.0f + __expf(-perc[c] * 10.0f));

    float k[9], bk[9];
    #pragma unroll
    for (int i = 0; i < 9; ++i) {
        k[i]  = kern[c * 9 + i];
        bk[i] = k[i] * biasv;
    }

    const float* plane = x + (size_t)bc * (H_ * W_);

    // ---- phase 1: 10 independent clamped-row loads (no consumers yet) ----
    f32x4 v[TH + 2];
    #pragma unroll
    for (int i = 0; i < TH + 2; ++i) {
        int yy  = y0 + i - 1;
        int yyc = yy < 0 ? 0 : (yy > H_ - 1 ? H_ - 1 : yy);
        v[i] = *reinterpret_cast<const f32x4*>(plane + yyc * W_ + x0);
    }

    // ---- y-pad rows: wholesale zero under uniform branch (raw pad = 0) ----
    if (ytile == 0)       v[0] = f32x4{ 0.0f, 0.0f, 0.0f, 0.0f };
    if (ytile == GYT - 1) v[TH + 1] = f32x4{ 0.0f, 0.0f, 0.0f, 0.0f };

    // ---- halos: one shuffle pair per row, built once ----
    float L[TH + 2], R[TH + 2];
    #pragma unroll
    for (int i = 0; i < TH + 2; ++i) {
        float l = __shfl_up(v[i].w, 1);    // prev lane's x0+3 == our x0-1
        float r = __shfl_down(v[i].x, 1);  // next lane's x0   == our x0+4
        L[i] = (gx > 0)  ? l : 0.0f;
        R[i] = (gx < 27) ? r : 0.0f;
    }

    float* oplane = out + (size_t)bc * (H_ * W_);

    // ---- compute: 8 output rows, window rows r..r+2 read L/v/R directly ----
    #pragma unroll
    for (int r = 0; r < TH; ++r) {
        // e[j][0..5] = window row r+j elements x0-1 .. x0+4
        float o[4];
        #pragma unroll
        for (int q = 0; q < 4; ++q) {
            float vmax, vmin;
            #pragma unroll
            for (int j = 0; j < 3; ++j) {
                const f32x4 vv = v[r + j];
                // window px x0+q-1, x0+q, x0+q+1 for this row
                float e0 = (q == 0) ? L[r + j] : ((q == 1) ? vv.x : ((q == 2) ? vv.y : vv.z));
                float e1 = (q == 0) ? vv.x : ((q == 1) ? vv.y : ((q == 2) ? vv.z : vv.w));
                float e2 = (q == 0) ? vv.y : ((q == 1) ? vv.z : ((q == 2) ? vv.w : R[r + j]));
                float t0 = fmaf(e0, k[3 * j],     bk[3 * j]);
                float t1 = fmaf(e1, k[3 * j + 1], bk[3 * j + 1]);
                float t2 = fmaf(e2, k[3 * j + 2], bk[3 * j + 2]);
                float mx = fmaxf(fmaxf(t0, t1), t2);
                float mn = fminf(fminf(t0, t1), t2);
                if (j == 0) { vmax = mx; vmin = mn; }
                else        { vmax = fmaxf(vmax, mx); vmin = fminf(vmin, mn); }
            }
            o[q] = fmaf(vmax - vmin, p, vmin) - biasv;
        }
        if (active) {
            f32x4 ov = { o[0], o[1], o[2], o[3] };
            *reinterpret_cast<f32x4*>(oplane + (y0 + r) * W_ + x0) = ov;
        }
    }
}

extern "C" void kernel_launch(void* const* d_in, const int* in_sizes, int n_in,
                              void* d_out, int out_size, void* d_ws, size_t ws_size,
                              hipStream_t stream) {
    const float* x    = (const float*)d_in[0];
    const float* kern = (const float*)d_in[1];
    const float* bias = (const float*)d_in[2];
    const float* perc = (const float*)d_in[3];
    float* out = (float*)d_out;

    // 14336 groups of 32 lanes = 458,752 threads
    const int threads = (B_ * C_ * GYT) * 32;
    const int block = 256;
    const int grid  = threads / block;     // 1792
    morph2d_kernel<<<grid, block, 0, stream>>>(x, kern, bias, perc, out);
}